// Round 2
// 168.956 us; speedup vs baseline: 1.1321x; 1.1321x over previous
//
#include <hip/hip_runtime.h>
#include <cstdint>
#include <cmath>

// RandomPhongShader: exact reproduction of JAX threefry-partitionable RNG +
// XLA CPU float32 numerics, fused shader.
//
// Round 10: round-9 wave compaction, with the two correctness bugs fixed.
//  - BUG 1 (race): the T/s1 LDS union interleaved wave partitions; a fast
//    wave's s1 init clobbered a slow wave's thresholds. FIX: four uniform
//    __syncthreads() at phase transitions; s1 init happens after the
//    barrier that ends all T reads.
//  - BUG 2 (overflow): argmax list needs 64*9=576 entries/wave, had 512.
//    FIX: listS[4][576].
//  - Compaction scheme unchanged from round 9:
//    * Heaviside: |dist| >= 0.55 -> noise-free outcome (|0.1*noise| <=
//      0.5421 exact-path bound); survivors compacted into a per-wave item
//      list (ballot/mbcnt exscan), processed by all 64 lanes.
//    * Argmax: zm[j] < max_zm - 1.0842 can never win; viable items
//      compacted; winner via LDS u64 atomicMax, key = score<<32 | (15-j)
//      (first-index tie-break); exact 2nd via atomicMax(min(key,old))
//      pairwise trick; validated best-second < BAND_A exact-redo fallback
//      preserved. V==1 pixels (incl. all-cnt0 -> bg) hash NOTHING.
//  - Numeric helpers verbatim from rounds 3-8.
//
// Shapes: N=8,H=256,W=256,K=8, NB_SAMPLES=4. Pixels P = N*H*W = 524288.
// partitionable bits(i) = o0 ^ o1 of threefry2x32(key, (0, i))
// split(key(1)): kh = cipher((0,1),(0,0)), ka = cipher((0,1),(0,1))

#pragma clang fp contract(off)

#define NPIX 524288
#define STRIDE_H 4194304u
#define STRIDE_A 4718592u
#define BAND_A 5e-5f
#define DET_THR 0.55f    // |dist| >= DET_THR  -> heaviside outcome is noise-free
#define ELIM_THR 1.10f   // zm gap > ELIM_THR  -> argmax candidate can never win

__device__ __forceinline__ uint32_t rotl32(uint32_t v, int n) {
  return (v << n) | (v >> (32 - n));   // v_alignbit_b32
}

__device__ __forceinline__ void tf2x32(uint32_t k0, uint32_t k1,
                                       uint32_t c0, uint32_t c1,
                                       uint32_t& o0, uint32_t& o1) {
  const uint32_t k2 = k0 ^ k1 ^ 0x1BD11BDAu;
  uint32_t x0 = c0 + k0, x1 = c1 + k1;
#define TFR(r) { x0 += x1; x1 = rotl32(x1, r); x1 ^= x0; }
  TFR(13) TFR(15) TFR(26) TFR(6)
  x0 += k1;  x1 += k2 + 1u;
  TFR(17) TFR(29) TFR(16) TFR(24)
  x0 += k2;  x1 += k0 + 2u;
  TFR(13) TFR(15) TFR(26) TFR(6)
  x0 += k0;  x1 += k1 + 3u;
  TFR(17) TFR(29) TFR(16) TFR(24)
  x0 += k1;  x1 += k2 + 4u;
  TFR(13) TFR(15) TFR(26) TFR(6)
  x0 += k2;  x1 += k0 + 5u;
#undef TFR
  o0 = x0; o1 = x1;
}

// ---- exact path (cold): rounds-3..8-validated numerics ----
__device__ __forceinline__ double fast_log(double z) {
  uint64_t b = __double_as_longlong(z);
  int E = (int)(b >> 52) - 1023;
  double m = __longlong_as_double((b & 0x000FFFFFFFFFFFFFULL) |
                                  0x3FF0000000000000ULL);  // [1,2)
  bool c = m > 1.4142135623730951;
  m = c ? m * 0.5 : m;   // exact
  E = c ? E + 1 : E;
  double d = m + 1.0;
  double r = __builtin_amdgcn_rcp(d);
  r = fma(r, fma(-d, r, 1.0), r);
  r = fma(r, fma(-d, r, 1.0), r);              // ~2e-16 rel
  double s = (m - 1.0) * r;
  double u = s * s;
  double p = 1.0 / 19.0;
  p = fma(p, u, 1.0 / 17.0);
  p = fma(p, u, 1.0 / 15.0);
  p = fma(p, u, 1.0 / 13.0);
  p = fma(p, u, 1.0 / 11.0);
  p = fma(p, u, 1.0 / 9.0);
  p = fma(p, u, 1.0 / 7.0);
  p = fma(p, u, 1.0 / 5.0);
  p = fma(p, u, 1.0 / 3.0);
  p = fma(p, u, 1.0);
  double lm = (2.0 * s) * p;
  const double LN2_HI = 6.93147180369123816490e-01;
  const double LN2_LO = 1.90821492927058770002e-10;
  double e = (double)E;
  return fma(e, LN2_HI, fma(e, LN2_LO, lm));
}

__device__ __forceinline__ float normal_exact(uint32_t bits) {
  float f = __uint_as_float((bits >> 9) | 0x3f800000u) - 1.0f;  // exact
  const float lo = __uint_as_float(0xBF7FFFFFu);
  float v = __fadd_rn(__fmul_rn(f, 2.0f), lo);
  v = fmaxf(lo, v);
  float t = -__fmul_rn(v, v);
  float taylor = __fmul_rn(__fadd_rn(__fmul_rn(-0.5f, t), 1.0f), t);
  float lg = (float)fast_log((double)__fadd_rn(t, 1.0f));
  float l1p = (fabsf(t) < 1e-4f) ? taylor : lg;
  float w = -l1p;
  const bool lt = w < 5.0f;
  float ww = lt ? __fsub_rn(w, 2.5f) : __fsub_rn(__fsqrt_rn(w), 3.0f);
  float p  = lt ? 2.81022636e-08f : -0.000200214257f;
  p = __fadd_rn(lt ?  3.43273939e-07f :  0.000100950558f, __fmul_rn(p, ww));
  p = __fadd_rn(lt ? -3.5233877e-06f  :  0.00134934322f,  __fmul_rn(p, ww));
  p = __fadd_rn(lt ? -4.39150654e-06f : -0.00367342844f,  __fmul_rn(p, ww));
  p = __fadd_rn(lt ?  0.00021858087f  :  0.00573950773f,  __fmul_rn(p, ww));
  p = __fadd_rn(lt ? -0.00125372503f  : -0.0076224613f,   __fmul_rn(p, ww));
  p = __fadd_rn(lt ? -0.00417768164f  :  0.00943887047f,  __fmul_rn(p, ww));
  p = __fadd_rn(lt ?  0.246640727f    :  1.00167406f,     __fmul_rn(p, ww));
  p = __fadd_rn(lt ?  1.50140941f     :  2.83297682f,     __fmul_rn(p, ww));
  return __fmul_rn(__uint_as_float(0x3FB504F3u), __fmul_rn(p, v));
}

// ---- approx argmax score (hot). v kept bit-exact; log/poly approximated;
// |score_fast - score_exact| <~ 4e-6; margin BAND_A = 5e-5 -> >=12x safety.
__device__ __forceinline__ float score_fast(uint32_t bits, float zmj) {
  float f = __uint_as_float((bits >> 9) | 0x3f800000u) - 1.0f;  // exact
  const float lo = __uint_as_float(0xBF7FFFFFu);
  float v = fmaxf(lo, __fmaf_rn(f, 2.0f, lo));
  float t = -__fmul_rn(v, v);
  float u = __fadd_rn(t, 1.0f);
  float L = __builtin_amdgcn_logf(u);            // log2(u), <=0
  float ww = __fmaf_rn(-0.69314718f, L, -2.5f);  // w - 2.5
  float p = 2.81022636e-08f;
  p = __fmaf_rn(p, ww,  3.43273939e-07f);
  p = __fmaf_rn(p, ww, -3.5233877e-06f);
  p = __fmaf_rn(p, ww, -4.39150654e-06f);
  p = __fmaf_rn(p, ww,  0.00021858087f);
  p = __fmaf_rn(p, ww, -0.00125372503f);
  p = __fmaf_rn(p, ww, -0.00417768164f);
  p = __fmaf_rn(p, ww,  0.246640727f);
  p = __fmaf_rn(p, ww,  1.50140941f);
  if (__builtin_expect(__ballot(L <= -7.2134752f) != 0ull, 0)) {  // w>=5
    float w = __fmul_rn(-0.69314718f, L);
    float w2 = __builtin_amdgcn_sqrtf(w) - 3.0f;
    float q = -0.000200214257f;
    q = __fmaf_rn(q, w2,  0.000100950558f);
    q = __fmaf_rn(q, w2,  0.00134934322f);
    q = __fmaf_rn(q, w2, -0.00367342844f);
    q = __fmaf_rn(q, w2,  0.00573950773f);
    q = __fmaf_rn(q, w2, -0.0076224613f);
    q = __fmaf_rn(q, w2,  0.00943887047f);
    q = __fmaf_rn(q, w2,  1.00167406f);
    q = __fmaf_rn(q, w2,  2.83297682f);
    p = (L <= -7.2134752f) ? q : p;
  }
  return __fmaf_rn(__fmul_rn(p, v), 0.14142136f, zmj);  // zm + 0.1*sqrt2*p*v
}

// ---- order-preserving f32 <-> u32 map (for LDS atomicMax keys) ----
__device__ __forceinline__ uint32_t map_f32(float s) {
  uint32_t u = __float_as_uint(s);
  return u ^ ((uint32_t)((int32_t)u >> 31) | 0x80000000u);
}
__device__ __forceinline__ float unmap_f32(uint32_t m) {
  uint32_t u = m ^ ((uint32_t)((int32_t)(~m) >> 31) | 0x80000000u);
  return __uint_as_float(u);
}

// ---- wave-wide exclusive prefix sum of v in [0,15] via 4 ballots ----
__device__ __forceinline__ int wave_exscan4(int v, int& total) {
  int pre = 0; total = 0;
  #pragma unroll
  for (int b = 0; b < 4; ++b) {
    unsigned long long bl = __ballot(((v >> b) & 1) != 0);
    int below = (int)__builtin_amdgcn_mbcnt_hi(
        (uint32_t)(bl >> 32), __builtin_amdgcn_mbcnt_lo((uint32_t)bl, 0u));
    pre += below << b;
    total += (int)__popcll(bl) << b;
  }
  return pre;
}

__global__ __launch_bounds__(256) void RandomPhongShader_kernel(
    const float* __restrict__ colors,   // (P,8,3)
    const float* __restrict__ dists,    // (P,8)
    const float* __restrict__ zbuf,     // (P,8)
    const int*   __restrict__ p2f,      // (P,8)
    const float* __restrict__ bg,       // (3,)
    float* __restrict__ out)            // (P,4)
{
  // LDS: 8192 (T / argmax best-key, time-shared; race fixed by barriers)
  //      + 4096 (second-score) + 9216 (zm) + 2048 (cnt) + 4608 (list)
  //      = 28160 B
  union SlotU {
    int T[256][8];                      // phase 0/1: integer thresholds
    unsigned long long s1[4][256];      // phase 3: best (score<<32 | 15-j)
  };
  __shared__ SlotU SU;
  __shared__ unsigned int S2[4][256];   // phase 3: 2nd-best mapped score
  __shared__ float zmS[256][9];         // z_map, for item scoring + redo
  __shared__ __align__(8) unsigned char cntS[256][8];   // heaviside counts
  __shared__ unsigned short listS[4][576];              // per-wave item list

  const int tid  = threadIdx.x;
  const int lane = tid & 63;
  const int wv   = tid >> 6;
  const int P    = blockIdx.x * 256 + tid;       // grid exact: 2048*256
  const int Pw   = blockIdx.x * 256 + (wv << 6); // wave's base pixel

  uint32_t kh0, kh1, ka0, ka1;                   // constant-folded
  tf2x32(0u, 1u, 0u, 0u, kh0, kh1);
  tf2x32(0u, 1u, 0u, 1u, ka0, ka1);

  // ---- phase 0: integer thresholds + determinism classification.
  // decision (bits>>9) >= T, T = ceil((erf(10*d/sqrt2)+0.99999994)*2^22);
  // band +-6 units covers erf err + RN wiggle + conversion (rounds 6-8 ok).
  // |0.1*noise| <= 0.5421 (exact-path bound), so |d| >= 0.55 is noise-free.
  uint32_t ndm = 0, p4m = 0;   // nondeterministic-k mask, guaranteed-pass mask
  {
    const float4* d4 = reinterpret_cast<const float4*>(dists + (size_t)P * 8);
    float4 a = d4[0], b = d4[1];
    float dk[8] = {a.x,a.y,a.z,a.w,b.x,b.y,b.z,b.w};
    int t8[8];
    #pragma unroll
    for (int k = 0; k < 8; ++k) {
      float y = fabsf(dk[k]) * 7.0710678f;
      float tt = __builtin_amdgcn_rcpf(__fmaf_rn(0.3275911f, y, 1.0f));
      float ex = __builtin_amdgcn_exp2f(__fmul_rn(-1.4426951f, y * y));
      float pp = 1.061405429f;
      pp = __fmaf_rn(pp, tt, -1.453152027f);
      pp = __fmaf_rn(pp, tt,  1.421413741f);
      pp = __fmaf_rn(pp, tt, -0.284496736f);
      pp = __fmaf_rn(pp, tt,  0.254829592f);
      float er = __fmaf_rn(-pp * tt, ex, 1.0f);
      float vs = copysignf(er, dk[k]);
      int T = (int)ceilf(__fmul_rn(__fadd_rn(vs, 0.99999994f), 4194304.0f));
      t8[k] = T - 6;
      ndm |= (fabsf(dk[k]) < DET_THR) ? (1u << k) : 0u;
      p4m |= (dk[k] <= -DET_THR) ? (1u << k) : 0u;
    }
    int4* tp = reinterpret_cast<int4*>(&SU.T[tid][0]);
    tp[0] = make_int4(t8[0], t8[1], t8[2], t8[3]);
    tp[1] = make_int4(t8[4], t8[5], t8[6], t8[7]);
  }

  // ---- phase 1a: build heaviside item list ----
  int Wtot;
  {
    int off = wave_exscan4(__builtin_popcount(ndm), Wtot);
    uint32_t m = ndm;
    int idx = off;
    while (m) {                       // write own nondet (lane,k) items
      int k = __builtin_ctz(m); m &= m - 1;
      listS[wv][idx++] = (unsigned short)((lane << 3) | k);
    }
  }
  __syncthreads();   // B1: T + list visible

  // ---- phase 1b: heaviside counts, compacted across the wave ----
  {
    const int trips = (Wtot + 63) >> 6;
    #pragma unroll 1
    for (int t = 0; t < trips; ++t) {
      const int i = (t << 6) + lane;
      const bool valid = i < Wtot;
      const unsigned short itm = listS[wv][valid ? i : 0];
      const int ow = itm >> 3, k = itm & 7;
      const int oTid = (wv << 6) | ow;
      const int To = SU.T[oTid][k];
      const uint32_t base = (uint32_t)(Pw + ow) * 8u + (uint32_t)k;
      uint32_t cnt = 0; bool band = false;
      #pragma unroll
      for (int s = 0; s < 4; ++s) {
        uint32_t o0, o1;
        tf2x32(kh0, kh1, 0u, base + (uint32_t)s * STRIDE_H, o0, o1);
        int mm = (int)((o0 ^ o1) >> 9);
        int sub = mm - To;
        cnt += (sub >= 6) ? 1u : 0u;
        band |= ((uint32_t)sub <= 12u);
      }
      if (__builtin_expect(__ballot(band && valid) != 0ull, 0)) {
        if (band && valid) {   // exec-masked exact redo of this item (rolled)
          float x = -dists[(size_t)base];     // cold reload
          uint32_t c2 = 0;
          #pragma unroll 1
          for (int s = 0; s < 4; ++s) {
            uint32_t o0, o1;
            tf2x32(kh0, kh1, 0u, base + (uint32_t)s * STRIDE_H, o0, o1);
            float nz = normal_exact(o0 ^ o1);
            c2 += (__fadd_rn(x, __fmul_rn(0.1f, nz)) >= 0.0f) ? 1u : 0u;
          }
          cnt = c2;
        }
      }
      if (valid) cntS[oTid][k] = (unsigned char)cnt;
    }
  }
  __syncthreads();   // B2: cnt visible; ALL waves' T reads done (union safe)

  // ---- phase 2: mask, z_inv, z_map (exact; __fdiv_rn as in rounds 1-8) ----
  uint32_t msk;   // bit k = (p2f[k] >= 0)
  {
    const int4* m4 = reinterpret_cast<const int4*>(p2f + (size_t)P * 8);
    int4 f = m4[0], g = m4[1];
    msk  = (f.x >= 0 ? 1u : 0u) | (f.y >= 0 ? 2u : 0u)
         | (f.z >= 0 ? 4u : 0u) | (f.w >= 0 ? 8u : 0u)
         | (g.x >= 0 ? 16u : 0u) | (g.y >= 0 ? 32u : 0u)
         | (g.z >= 0 ? 64u : 0u) | (g.w >= 0 ? 128u : 0u);
  }
  float zinv[8], zmax;
  {
    const float4* z4 = reinterpret_cast<const float4*>(zbuf + (size_t)P * 8);
    float4 c = z4[0], e = z4[1];
    float zk[8] = {c.x,c.y,c.z,c.w,e.x,e.y,e.z,e.w};
    #pragma unroll
    for (int k = 0; k < 8; ++k) {
      const float m = ((msk >> k) & 1u) ? 1.0f : 0.0f;
      float zi = __fmul_rn(__fdiv_rn(__fsub_rn(100.0f, zk[k]), 99.0f), m);
      zinv[k] = zi;
      zmax = (k == 0) ? zi : fmaxf(zmax, zi);
    }
  }
  zmax = fmaxf(zmax, 1e-10f);

  const float lg0 = (float)-23.025850916589025;  // log(1e-10f)
  const float lg1 = (float)-1.3862943611198906;  // log(0.25)
  const float lg2 = (float)-0.6931471805599453;  // log(0.5)
  const float lg3 = (float)-0.2876820724517809;  // log(0.75)

  const uint2 cg = *reinterpret_cast<const uint2*>(&cntS[tid][0]);
  float alpha = 1.0f;
  float zm[9];
  #pragma unroll
  for (int k = 0; k < 8; ++k) {
    const uint32_t byte_ = ((k < 4 ? cg.x : cg.y) >> (8 * (k & 3))) & 0xffu;
    const int cntk = ((ndm >> k) & 1u) ? (int)byte_
                    : ((((p4m >> k) & 1u) != 0u) ? 4 : 0);
    const bool mb = ((msk >> k) & 1u) != 0u;
    const float pm = mb ? __fmul_rn((float)cntk, 0.25f) : 0.0f;
    alpha *= (1.0f - pm);  // exact
    const int i = mb ? cntk : 0;
    const float lg = (i == 0) ? lg0 : (i == 1) ? lg1 : (i == 2) ? lg2
                   : (i == 3) ? lg3 : 0.0f;
    zm[k] = __fadd_rn(lg, __fdiv_rn(__fsub_rn(zinv[k], zmax), 0.1f));
    zmS[tid][k] = zm[k];
  }
  zm[8] = __fdiv_rn(__fsub_rn(1e-10f, zmax), 0.1f);
  zmS[tid][8] = zm[8];
  // zinv, msk, cnt dead here; live: zm[9], alpha.

  // ---- phase 3a: viability, item list, slot init ----
  // score_j = zm[j] + noise, |noise| <= 0.5421 -> zm[j] < bz - 1.0842 never
  // wins. V==1 (incl. all-cnt0 -> bg) is a deterministic winner, 0 hashes.
  float bz = zm[0];
  #pragma unroll
  for (int j = 1; j < 9; ++j) bz = fmaxf(bz, zm[j]);
  const float thr = __fsub_rn(bz, ELIM_THR);
  uint32_t vm = 0;
  #pragma unroll
  for (int j = 0; j < 9; ++j) vm |= (zm[j] >= thr) ? (1u << j) : 0u;
  const int V  = __builtin_popcount(vm);
  const int j0 = __builtin_ctz(vm);

  int W3;
  {
    int off3 = wave_exscan4((V >= 2) ? V : 0, W3);
    uint32_t m = (V >= 2) ? vm : 0u;
    int idx = off3;
    while (m) {
      int j = __builtin_ctz(m); m &= m - 1;
      listS[wv][idx++] = (unsigned short)((lane << 4) | j);
    }
  }
  #pragma unroll
  for (int s = 0; s < 4; ++s) { SU.s1[s][tid] = 0ull; S2[s][tid] = 0u; }
  __syncthreads();   // B3: zm + list + slot init visible

  // ---- phase 3b: compacted scoring with LDS max/second slots ----
  const int trips3 = (W3 + 63) >> 6;
  #pragma unroll 1
  for (int t = 0; t < trips3; ++t) {
    const int i = (t << 6) + lane;
    const bool valid = i < W3;
    const unsigned short itm = listS[wv][valid ? i : 0];
    const int ow = itm >> 4, j = itm & 15;
    const int oTid = (wv << 6) | ow;
    const float zo = zmS[oTid][j];
    const uint32_t cb3 = (uint32_t)(Pw + ow) * 9u + (uint32_t)j;
    const unsigned long long jtag = (unsigned long long)(15 - j);
    #pragma unroll
    for (int s = 0; s < 4; ++s) {
      uint32_t o0, o1;
      tf2x32(ka0, ka1, 0u, cb3 + (uint32_t)s * STRIDE_A, o0, o1);
      float sc = score_fast(o0 ^ o1, zo);
      unsigned long long key = ((unsigned long long)map_f32(sc) << 32) | jtag;
      if (valid) {
        // best + exact-second: slot2 ends at 2nd-largest key's score for any
        // serialization (min(key, old-best) pairwise trick). Keys distinct
        // (jtag), so equal-score top-two -> s1f==s2f -> band fallback.
        unsigned long long old = atomicMax(&SU.s1[s][oTid], key);
        unsigned long long mn = key < old ? key : old;
        atomicMax(&S2[s][oTid], (unsigned int)(mn >> 32));
      }
    }
  }
  __syncthreads();   // B4: slots final

  // ---- finalize argmax: read slots, band fallback, pack winners ----
  uint32_t amPack = 0;
  const uint32_t cAo = (uint32_t)P * 9u;
  #pragma unroll 1
  for (int s = 0; s < 4; ++s) {
    int js;
    bool fl = false;
    if (V >= 2) {
      const unsigned long long b1 = SU.s1[s][tid];
      js = 15 - (int)(b1 & 0xFFFFu);
      const float s1f = unmap_f32((uint32_t)(b1 >> 32));
      const float s2f = unmap_f32(S2[s][tid]);
      fl = __fsub_rn(s1f, s2f) < BAND_A;
    } else {
      js = j0;   // deterministic winner (incl. bg when all cnt==0)
    }
    if (__builtin_expect(__ballot(fl) != 0ull, 0)) {
      if (fl) {   // exec-masked exact redo of this sample, ROLLED (LDS zm)
        int ame = 0;
        float be = -3.4e38f;
        #pragma unroll 1
        for (int j = 0; j < 9; ++j) {
          uint32_t o0, o1;
          tf2x32(ka0, ka1, 0u, cAo + (uint32_t)s * STRIDE_A + (uint32_t)j,
                 o0, o1);
          float nz = normal_exact(o0 ^ o1);
          float ve = __fadd_rn(zmS[tid][j], __fmul_rn(0.1f, nz));
          bool g = ve > be;
          be = g ? ve : be;
          ame = g ? j : ame;
        }
        js = ame;
      }
    }
    amPack += 1u << (3 * js);
  }
  // zm dead here; live: amPack, alpha.

  // ---- phase 4: epilogue ----
  float rgb[3] = {0.0f, 0.0f, 0.0f};
  {
    const float4* c4 = reinterpret_cast<const float4*>(colors + (size_t)P * 24);
    float cc[24];
    #pragma unroll
    for (int q = 0; q < 6; ++q) {
      float4 t = c4[q];
      cc[q*4+0]=t.x; cc[q*4+1]=t.y; cc[q*4+2]=t.z; cc[q*4+3]=t.w;
    }
    #pragma unroll
    for (int c = 0; c < 3; ++c) {
      float acc = 0.0f;
      #pragma unroll
      for (int k = 0; k < 8; ++k) {
        float wk = __fmul_rn(0.25f, (float)((amPack >> (3 * k)) & 7u));
        acc = __fadd_rn(acc, __fmul_rn(wk, cc[k * 3 + c]));
      }
      float wb = __fmul_rn(0.25f, (float)((amPack >> 24) & 7u));
      rgb[c] = __fadd_rn(acc, __fmul_rn(wb, bg[c]));
    }
  }

  float4 o;
  o.x = rgb[0]; o.y = rgb[1]; o.z = rgb[2];
  o.w = __fsub_rn(1.0f, alpha);
  reinterpret_cast<float4*>(out)[P] = o;
}

extern "C" void kernel_launch(void* const* d_in, const int* in_sizes, int n_in,
                              void* d_out, int out_size, void* d_ws, size_t ws_size,
                              hipStream_t stream) {
  const float* colors = (const float*)d_in[0];
  const float* dists  = (const float*)d_in[1];
  const float* zbuf   = (const float*)d_in[2];
  const int*   p2f    = (const int*)d_in[3];
  const float* bg     = (const float*)d_in[4];
  float* out = (float*)d_out;
  dim3 grid(NPIX / 256), block(256);
  hipLaunchKernelGGL(RandomPhongShader_kernel, grid, block, 0, stream,
                     colors, dists, zbuf, p2f, bg, out);
}

// Round 3
// 168.621 us; speedup vs baseline: 1.1344x; 1.0020x over previous
//
#include <hip/hip_runtime.h>
#include <cstdint>
#include <cmath>

// RandomPhongShader: exact reproduction of JAX threefry-partitionable RNG +
// XLA CPU float32 numerics, fused shader.
//
// Round 11: wave-private everything -- no __syncthreads, u32 packed argmax
// slots, conflict-free slot layout, lazy erf.
//  - T is no longer staged in LDS: the processing lane recomputes the
//    integer threshold from a global dists reload with the IDENTICAL
//    instruction sequence (bit-identical T). This removes the only
//    cross-wave LDS data; every remaining LDS structure is wave-private,
//    so the 4 __syncthreads are replaced by per-wave DS-order +
//    s_waitcnt lgkmcnt(0) fences (CDNA DS ops of one wave execute in
//    order). Saves ~4.6 unused erf evaluations per pixel too.
//  - Argmax slots: u32 key = (order-mapped score & ~0xF) | (15-j).
//    Bucket width <= 16*ULP(|s|<64) = 6.1e-5. Band test widened to
//    BAND_PACK = 1.25e-4 >= BAND_A + bucket width: trusted fast path
//    still implies exact order (bucket_diff>=1.25e-4 => exact_diff>0);
//    same-bucket top-two unmaps equal => diff 0 => exact redo. Slots
//    laid out [wave][owner][s]: one lane's 4 sample-atomics hit 4
//    consecutive banks (round-10 layout had s-stride 2048B = same bank,
//    a guaranteed 4-way self-conflict -> 4.2M conflict cycles).
//  - LDS 28160 -> 24064 B => 6 blocks/CU (was 5).
//  - Compaction scheme + numeric helpers otherwise verbatim round 10.
//
// Shapes: N=8,H=256,W=256,K=8, NB_SAMPLES=4. Pixels P = N*H*W = 524288.
// partitionable bits(i) = o0 ^ o1 of threefry2x32(key, (0, i))
// split(key(1)): kh = cipher((0,1),(0,0)), ka = cipher((0,1),(0,1))

#pragma clang fp contract(off)

#define NPIX 524288
#define STRIDE_H 4194304u
#define STRIDE_A 4718592u
#define BAND_A 5e-5f
#define BAND_PACK 1.25e-4f   // BAND_A + 16*ULP(64) bucket width, + margin
#define KEY_MASK 0xFFFFFFF0u
#define DET_THR 0.55f    // |dist| >= DET_THR  -> heaviside outcome is noise-free
#define ELIM_THR 1.10f   // zm gap > ELIM_THR  -> argmax candidate can never win

// Per-wave phase fence: drain this wave's DS ops, block compiler motion.
#define WAVE_FENCE() do {                                   \
    asm volatile("s_waitcnt lgkmcnt(0)" ::: "memory");      \
    __builtin_amdgcn_sched_barrier(0);                      \
  } while (0)

__device__ __forceinline__ uint32_t rotl32(uint32_t v, int n) {
  return (v << n) | (v >> (32 - n));   // v_alignbit_b32
}

__device__ __forceinline__ void tf2x32(uint32_t k0, uint32_t k1,
                                       uint32_t c0, uint32_t c1,
                                       uint32_t& o0, uint32_t& o1) {
  const uint32_t k2 = k0 ^ k1 ^ 0x1BD11BDAu;
  uint32_t x0 = c0 + k0, x1 = c1 + k1;
#define TFR(r) { x0 += x1; x1 = rotl32(x1, r); x1 ^= x0; }
  TFR(13) TFR(15) TFR(26) TFR(6)
  x0 += k1;  x1 += k2 + 1u;
  TFR(17) TFR(29) TFR(16) TFR(24)
  x0 += k2;  x1 += k0 + 2u;
  TFR(13) TFR(15) TFR(26) TFR(6)
  x0 += k0;  x1 += k1 + 3u;
  TFR(17) TFR(29) TFR(16) TFR(24)
  x0 += k1;  x1 += k2 + 4u;
  TFR(13) TFR(15) TFR(26) TFR(6)
  x0 += k2;  x1 += k0 + 5u;
#undef TFR
  o0 = x0; o1 = x1;
}

// ---- exact path (cold): rounds-3..10-validated numerics ----
__device__ __forceinline__ double fast_log(double z) {
  uint64_t b = __double_as_longlong(z);
  int E = (int)(b >> 52) - 1023;
  double m = __longlong_as_double((b & 0x000FFFFFFFFFFFFFULL) |
                                  0x3FF0000000000000ULL);  // [1,2)
  bool c = m > 1.4142135623730951;
  m = c ? m * 0.5 : m;   // exact
  E = c ? E + 1 : E;
  double d = m + 1.0;
  double r = __builtin_amdgcn_rcp(d);
  r = fma(r, fma(-d, r, 1.0), r);
  r = fma(r, fma(-d, r, 1.0), r);              // ~2e-16 rel
  double s = (m - 1.0) * r;
  double u = s * s;
  double p = 1.0 / 19.0;
  p = fma(p, u, 1.0 / 17.0);
  p = fma(p, u, 1.0 / 15.0);
  p = fma(p, u, 1.0 / 13.0);
  p = fma(p, u, 1.0 / 11.0);
  p = fma(p, u, 1.0 / 9.0);
  p = fma(p, u, 1.0 / 7.0);
  p = fma(p, u, 1.0 / 5.0);
  p = fma(p, u, 1.0 / 3.0);
  p = fma(p, u, 1.0);
  double lm = (2.0 * s) * p;
  const double LN2_HI = 6.93147180369123816490e-01;
  const double LN2_LO = 1.90821492927058770002e-10;
  double e = (double)E;
  return fma(e, LN2_HI, fma(e, LN2_LO, lm));
}

__device__ __forceinline__ float normal_exact(uint32_t bits) {
  float f = __uint_as_float((bits >> 9) | 0x3f800000u) - 1.0f;  // exact
  const float lo = __uint_as_float(0xBF7FFFFFu);
  float v = __fadd_rn(__fmul_rn(f, 2.0f), lo);
  v = fmaxf(lo, v);
  float t = -__fmul_rn(v, v);
  float taylor = __fmul_rn(__fadd_rn(__fmul_rn(-0.5f, t), 1.0f), t);
  float lg = (float)fast_log((double)__fadd_rn(t, 1.0f));
  float l1p = (fabsf(t) < 1e-4f) ? taylor : lg;
  float w = -l1p;
  const bool lt = w < 5.0f;
  float ww = lt ? __fsub_rn(w, 2.5f) : __fsub_rn(__fsqrt_rn(w), 3.0f);
  float p  = lt ? 2.81022636e-08f : -0.000200214257f;
  p = __fadd_rn(lt ?  3.43273939e-07f :  0.000100950558f, __fmul_rn(p, ww));
  p = __fadd_rn(lt ? -3.5233877e-06f  :  0.00134934322f,  __fmul_rn(p, ww));
  p = __fadd_rn(lt ? -4.39150654e-06f : -0.00367342844f,  __fmul_rn(p, ww));
  p = __fadd_rn(lt ?  0.00021858087f  :  0.00573950773f,  __fmul_rn(p, ww));
  p = __fadd_rn(lt ? -0.00125372503f  : -0.0076224613f,   __fmul_rn(p, ww));
  p = __fadd_rn(lt ? -0.00417768164f  :  0.00943887047f,  __fmul_rn(p, ww));
  p = __fadd_rn(lt ?  0.246640727f    :  1.00167406f,     __fmul_rn(p, ww));
  p = __fadd_rn(lt ?  1.50140941f     :  2.83297682f,     __fmul_rn(p, ww));
  return __fmul_rn(__uint_as_float(0x3FB504F3u), __fmul_rn(p, v));
}

// ---- approx argmax score (hot). v kept bit-exact; log/poly approximated;
// |score_fast - score_exact| <~ 4e-6; margin BAND_A = 5e-5 -> >=12x safety.
__device__ __forceinline__ float score_fast(uint32_t bits, float zmj) {
  float f = __uint_as_float((bits >> 9) | 0x3f800000u) - 1.0f;  // exact
  const float lo = __uint_as_float(0xBF7FFFFFu);
  float v = fmaxf(lo, __fmaf_rn(f, 2.0f, lo));
  float t = -__fmul_rn(v, v);
  float u = __fadd_rn(t, 1.0f);
  float L = __builtin_amdgcn_logf(u);            // log2(u), <=0
  float ww = __fmaf_rn(-0.69314718f, L, -2.5f);  // w - 2.5
  float p = 2.81022636e-08f;
  p = __fmaf_rn(p, ww,  3.43273939e-07f);
  p = __fmaf_rn(p, ww, -3.5233877e-06f);
  p = __fmaf_rn(p, ww, -4.39150654e-06f);
  p = __fmaf_rn(p, ww,  0.00021858087f);
  p = __fmaf_rn(p, ww, -0.00125372503f);
  p = __fmaf_rn(p, ww, -0.00417768164f);
  p = __fmaf_rn(p, ww,  0.246640727f);
  p = __fmaf_rn(p, ww,  1.50140941f);
  if (__builtin_expect(__ballot(L <= -7.2134752f) != 0ull, 0)) {  // w>=5
    float w = __fmul_rn(-0.69314718f, L);
    float w2 = __builtin_amdgcn_sqrtf(w) - 3.0f;
    float q = -0.000200214257f;
    q = __fmaf_rn(q, w2,  0.000100950558f);
    q = __fmaf_rn(q, w2,  0.00134934322f);
    q = __fmaf_rn(q, w2, -0.00367342844f);
    q = __fmaf_rn(q, w2,  0.00573950773f);
    q = __fmaf_rn(q, w2, -0.0076224613f);
    q = __fmaf_rn(q, w2,  0.00943887047f);
    q = __fmaf_rn(q, w2,  1.00167406f);
    q = __fmaf_rn(q, w2,  2.83297682f);
    p = (L <= -7.2134752f) ? q : p;
  }
  return __fmaf_rn(__fmul_rn(p, v), 0.14142136f, zmj);  // zm + 0.1*sqrt2*p*v
}

// ---- order-preserving f32 <-> u32 map (for LDS atomicMax keys) ----
__device__ __forceinline__ uint32_t map_f32(float s) {
  uint32_t u = __float_as_uint(s);
  return u ^ ((uint32_t)((int32_t)u >> 31) | 0x80000000u);
}
__device__ __forceinline__ float unmap_f32(uint32_t m) {
  uint32_t u = m ^ ((uint32_t)((int32_t)(~m) >> 31) | 0x80000000u);
  return __uint_as_float(u);
}

// ---- integer heaviside threshold from dist (bit-identical everywhere) ----
__device__ __forceinline__ int thresh_m6(float d) {
  float y = fabsf(d) * 7.0710678f;
  float tt = __builtin_amdgcn_rcpf(__fmaf_rn(0.3275911f, y, 1.0f));
  float ex = __builtin_amdgcn_exp2f(__fmul_rn(-1.4426951f, y * y));
  float pp = 1.061405429f;
  pp = __fmaf_rn(pp, tt, -1.453152027f);
  pp = __fmaf_rn(pp, tt,  1.421413741f);
  pp = __fmaf_rn(pp, tt, -0.284496736f);
  pp = __fmaf_rn(pp, tt,  0.254829592f);
  float er = __fmaf_rn(-pp * tt, ex, 1.0f);
  float vs = copysignf(er, d);
  int T = (int)ceilf(__fmul_rn(__fadd_rn(vs, 0.99999994f), 4194304.0f));
  return T - 6;
}

// ---- wave-wide exclusive prefix sum of v in [0,15] via 4 ballots ----
__device__ __forceinline__ int wave_exscan4(int v, int& total) {
  int pre = 0; total = 0;
  #pragma unroll
  for (int b = 0; b < 4; ++b) {
    unsigned long long bl = __ballot(((v >> b) & 1) != 0);
    int below = (int)__builtin_amdgcn_mbcnt_hi(
        (uint32_t)(bl >> 32), __builtin_amdgcn_mbcnt_lo((uint32_t)bl, 0u));
    pre += below << b;
    total += (int)__popcll(bl) << b;
  }
  return pre;
}

__global__ __launch_bounds__(256) void RandomPhongShader_kernel(
    const float* __restrict__ colors,   // (P,8,3)
    const float* __restrict__ dists,    // (P,8)
    const float* __restrict__ zbuf,     // (P,8)
    const int*   __restrict__ p2f,      // (P,8)
    const float* __restrict__ bg,       // (3,)
    float* __restrict__ out)            // (P,4)
{
  // LDS (ALL wave-private): zm 9216 + cnt 2048 + list 4608 + s1 4096 +
  // s2 4096 = 24064 B -> 6 blocks/CU.
  __shared__ float zmS[256][9];           // z_map (item scoring + redo)
  __shared__ __align__(8) unsigned char cntS[256][8];   // heaviside counts
  __shared__ unsigned short listS[4][576];              // per-wave item list
  __shared__ unsigned int s1S[4][64][4];  // best packed key, [wv][ow][s]
  __shared__ unsigned int s2S[4][64][4];  // 2nd-best packed key

  const int tid  = threadIdx.x;
  const int lane = tid & 63;
  const int wv   = tid >> 6;
  const int P    = blockIdx.x * 256 + tid;       // grid exact: 2048*256
  const int Pw   = blockIdx.x * 256 + (wv << 6); // wave's base pixel

  uint32_t kh0, kh1, ka0, ka1;                   // constant-folded
  tf2x32(0u, 1u, 0u, 0u, kh0, kh1);
  tf2x32(0u, 1u, 0u, 1u, ka0, ka1);

  // ---- phase 0: determinism classification only (no erf -- lazy).
  // |0.1*noise| <= 0.5421 (exact-path bound), so |d| >= 0.55 is noise-free.
  uint32_t ndm = 0, p4m = 0;   // nondeterministic-k mask, guaranteed-pass mask
  {
    const float4* d4 = reinterpret_cast<const float4*>(dists + (size_t)P * 8);
    float4 a = d4[0], b = d4[1];
    float dk[8] = {a.x,a.y,a.z,a.w,b.x,b.y,b.z,b.w};
    #pragma unroll
    for (int k = 0; k < 8; ++k) {
      ndm |= (fabsf(dk[k]) < DET_THR) ? (1u << k) : 0u;
      p4m |= (dk[k] <= -DET_THR) ? (1u << k) : 0u;
    }
  }

  // ---- phase 1a: build heaviside item list (wave-private) ----
  int Wtot;
  {
    int off = wave_exscan4(__builtin_popcount(ndm), Wtot);
    uint32_t m = ndm;
    int idx = off;
    while (m) {                       // write own nondet (lane,k) items
      int k = __builtin_ctz(m); m &= m - 1;
      listS[wv][idx++] = (unsigned short)((lane << 3) | k);
    }
  }
  WAVE_FENCE();   // F1: list visible (same-wave DS order)

  // ---- phase 1b: heaviside counts, compacted across the wave.
  // T recomputed per item from a global dists reload (bit-identical to the
  // phase-0 sequence of rounds 1-10; L1/L2-hit, hidden under the hashes).
  {
    const int trips = (Wtot + 63) >> 6;
    #pragma unroll 1
    for (int t = 0; t < trips; ++t) {
      const int i = (t << 6) + lane;
      const bool valid = i < Wtot;
      const unsigned short itm = listS[wv][valid ? i : 0];
      const int ow = itm >> 3, k = itm & 7;
      const int oTid = (wv << 6) | ow;
      const uint32_t base = (uint32_t)(Pw + ow) * 8u + (uint32_t)k;
      const float d = dists[(size_t)base];
      const int To = thresh_m6(d);
      uint32_t cnt = 0; bool band = false;
      #pragma unroll
      for (int s = 0; s < 4; ++s) {
        uint32_t o0, o1;
        tf2x32(kh0, kh1, 0u, base + (uint32_t)s * STRIDE_H, o0, o1);
        int mm = (int)((o0 ^ o1) >> 9);
        int sub = mm - To;
        cnt += (sub >= 6) ? 1u : 0u;
        band |= ((uint32_t)sub <= 12u);
      }
      if (__builtin_expect(__ballot(band && valid) != 0ull, 0)) {
        if (band && valid) {   // exec-masked exact redo of this item (rolled)
          float x = -d;
          uint32_t c2 = 0;
          #pragma unroll 1
          for (int s = 0; s < 4; ++s) {
            uint32_t o0, o1;
            tf2x32(kh0, kh1, 0u, base + (uint32_t)s * STRIDE_H, o0, o1);
            float nz = normal_exact(o0 ^ o1);
            c2 += (__fadd_rn(x, __fmul_rn(0.1f, nz)) >= 0.0f) ? 1u : 0u;
          }
          cnt = c2;
        }
      }
      if (valid) cntS[oTid][k] = (unsigned char)cnt;
    }
  }
  WAVE_FENCE();   // F2: cnt visible

  // ---- phase 2: mask, z_inv, z_map (exact; __fdiv_rn as in rounds 1-10) ----
  uint32_t msk;   // bit k = (p2f[k] >= 0)
  {
    const int4* m4 = reinterpret_cast<const int4*>(p2f + (size_t)P * 8);
    int4 f = m4[0], g = m4[1];
    msk  = (f.x >= 0 ? 1u : 0u) | (f.y >= 0 ? 2u : 0u)
         | (f.z >= 0 ? 4u : 0u) | (f.w >= 0 ? 8u : 0u)
         | (g.x >= 0 ? 16u : 0u) | (g.y >= 0 ? 32u : 0u)
         | (g.z >= 0 ? 64u : 0u) | (g.w >= 0 ? 128u : 0u);
  }
  float zinv[8], zmax;
  {
    const float4* z4 = reinterpret_cast<const float4*>(zbuf + (size_t)P * 8);
    float4 c = z4[0], e = z4[1];
    float zk[8] = {c.x,c.y,c.z,c.w,e.x,e.y,e.z,e.w};
    #pragma unroll
    for (int k = 0; k < 8; ++k) {
      const float m = ((msk >> k) & 1u) ? 1.0f : 0.0f;
      float zi = __fmul_rn(__fdiv_rn(__fsub_rn(100.0f, zk[k]), 99.0f), m);
      zinv[k] = zi;
      zmax = (k == 0) ? zi : fmaxf(zmax, zi);
    }
  }
  zmax = fmaxf(zmax, 1e-10f);

  const float lg0 = (float)-23.025850916589025;  // log(1e-10f)
  const float lg1 = (float)-1.3862943611198906;  // log(0.25)
  const float lg2 = (float)-0.6931471805599453;  // log(0.5)
  const float lg3 = (float)-0.2876820724517809;  // log(0.75)

  const uint2 cg = *reinterpret_cast<const uint2*>(&cntS[tid][0]);
  float alpha = 1.0f;
  float zm[9];
  #pragma unroll
  for (int k = 0; k < 8; ++k) {
    const uint32_t byte_ = ((k < 4 ? cg.x : cg.y) >> (8 * (k & 3))) & 0xffu;
    const int cntk = ((ndm >> k) & 1u) ? (int)byte_
                    : ((((p4m >> k) & 1u) != 0u) ? 4 : 0);
    const bool mb = ((msk >> k) & 1u) != 0u;
    const float pm = mb ? __fmul_rn((float)cntk, 0.25f) : 0.0f;
    alpha *= (1.0f - pm);  // exact
    const int i = mb ? cntk : 0;
    const float lg = (i == 0) ? lg0 : (i == 1) ? lg1 : (i == 2) ? lg2
                   : (i == 3) ? lg3 : 0.0f;
    zm[k] = __fadd_rn(lg, __fdiv_rn(__fsub_rn(zinv[k], zmax), 0.1f));
    zmS[tid][k] = zm[k];
  }
  zm[8] = __fdiv_rn(__fsub_rn(1e-10f, zmax), 0.1f);
  zmS[tid][8] = zm[8];
  // zinv, msk dead here; live: zm[9], alpha.

  // ---- phase 3a: viability, item list, slot init (all wave-private) ----
  // score_j = zm[j] + noise, |noise| <= 0.5421 -> zm[j] < bz - 1.0842 never
  // wins. V==1 (incl. all-cnt0 -> bg) is a deterministic winner, 0 hashes.
  float bz = zm[0];
  #pragma unroll
  for (int j = 1; j < 9; ++j) bz = fmaxf(bz, zm[j]);
  const float thr = __fsub_rn(bz, ELIM_THR);
  uint32_t vm = 0;
  #pragma unroll
  for (int j = 0; j < 9; ++j) vm |= (zm[j] >= thr) ? (1u << j) : 0u;
  const int V  = __builtin_popcount(vm);
  const int j0 = __builtin_ctz(vm);

  int W3;
  {
    int off3 = wave_exscan4((V >= 2) ? V : 0, W3);
    uint32_t m = (V >= 2) ? vm : 0u;
    int idx = off3;
    while (m) {
      int j = __builtin_ctz(m); m &= m - 1;
      listS[wv][idx++] = (unsigned short)((lane << 4) | j);
    }
  }
  #pragma unroll
  for (int s = 0; s < 4; ++s) { s1S[wv][lane][s] = 0u; s2S[wv][lane][s] = 0u; }
  WAVE_FENCE();   // F3: zm + list + slot init visible

  // ---- phase 3b: compacted scoring; u32 packed-key max/second slots.
  // key = (mapped score & ~0xF) | (15-j): bucket 16 ULP, first-index
  // tie-break inside a bucket; same-bucket top-two => s1f==s2f => redo.
  const int trips3 = (W3 + 63) >> 6;
  #pragma unroll 1
  for (int t = 0; t < trips3; ++t) {
    const int i = (t << 6) + lane;
    const bool valid = i < W3;
    const unsigned short itm = listS[wv][valid ? i : 0];
    const int ow = itm >> 4, j = itm & 15;
    const int oTid = (wv << 6) | ow;
    const float zo = zmS[oTid][j];
    const uint32_t cb3 = (uint32_t)(Pw + ow) * 9u + (uint32_t)j;
    const uint32_t jtag = (uint32_t)(15 - j);
    #pragma unroll
    for (int s = 0; s < 4; ++s) {
      uint32_t o0, o1;
      tf2x32(ka0, ka1, 0u, cb3 + (uint32_t)s * STRIDE_A, o0, o1);
      float sc = score_fast(o0 ^ o1, zo);
      uint32_t key = (map_f32(sc) & KEY_MASK) | jtag;
      if (valid) {
        // best + second: slot2 ends at 2nd-largest key for any serialization
        // (min(key, old-best) pairwise trick; keys distinct via jtag).
        uint32_t old = atomicMax(&s1S[wv][ow][s], key);
        uint32_t mn = key < old ? key : old;
        atomicMax(&s2S[wv][ow][s], mn);
      }
    }
  }
  WAVE_FENCE();   // F4: slots final

  // ---- finalize argmax: read slots, band fallback, pack winners ----
  uint32_t amPack = 0;
  const uint32_t cAo = (uint32_t)P * 9u;
  #pragma unroll 1
  for (int s = 0; s < 4; ++s) {
    int js;
    bool fl = false;
    if (V >= 2) {
      const uint32_t b1 = s1S[wv][lane][s];
      js = 15 - (int)(b1 & 0xFu);
      const float s1f = unmap_f32(b1 & KEY_MASK);
      const float s2f = unmap_f32(s2S[wv][lane][s] & KEY_MASK);
      fl = __fsub_rn(s1f, s2f) < BAND_PACK;
    } else {
      js = j0;   // deterministic winner (incl. bg when all cnt==0)
    }
    if (__builtin_expect(__ballot(fl) != 0ull, 0)) {
      if (fl) {   // exec-masked exact redo of this sample, ROLLED (LDS zm)
        int ame = 0;
        float be = -3.4e38f;
        #pragma unroll 1
        for (int j = 0; j < 9; ++j) {
          uint32_t o0, o1;
          tf2x32(ka0, ka1, 0u, cAo + (uint32_t)s * STRIDE_A + (uint32_t)j,
                 o0, o1);
          float nz = normal_exact(o0 ^ o1);
          float ve = __fadd_rn(zmS[tid][j], __fmul_rn(0.1f, nz));
          bool g = ve > be;
          be = g ? ve : be;
          ame = g ? j : ame;
        }
        js = ame;
      }
    }
    amPack += 1u << (3 * js);
  }
  // zm dead here; live: amPack, alpha.

  // ---- phase 4: epilogue ----
  float rgb[3] = {0.0f, 0.0f, 0.0f};
  {
    const float4* c4 = reinterpret_cast<const float4*>(colors + (size_t)P * 24);
    float cc[24];
    #pragma unroll
    for (int q = 0; q < 6; ++q) {
      float4 t = c4[q];
      cc[q*4+0]=t.x; cc[q*4+1]=t.y; cc[q*4+2]=t.z; cc[q*4+3]=t.w;
    }
    #pragma unroll
    for (int c = 0; c < 3; ++c) {
      float acc = 0.0f;
      #pragma unroll
      for (int k = 0; k < 8; ++k) {
        float wk = __fmul_rn(0.25f, (float)((amPack >> (3 * k)) & 7u));
        acc = __fadd_rn(acc, __fmul_rn(wk, cc[k * 3 + c]));
      }
      float wb = __fmul_rn(0.25f, (float)((amPack >> 24) & 7u));
      rgb[c] = __fadd_rn(acc, __fmul_rn(wb, bg[c]));
    }
  }

  float4 o;
  o.x = rgb[0]; o.y = rgb[1]; o.z = rgb[2];
  o.w = __fsub_rn(1.0f, alpha);
  reinterpret_cast<float4*>(out)[P] = o;
}

extern "C" void kernel_launch(void* const* d_in, const int* in_sizes, int n_in,
                              void* d_out, int out_size, void* d_ws, size_t ws_size,
                              hipStream_t stream) {
  const float* colors = (const float*)d_in[0];
  const float* dists  = (const float*)d_in[1];
  const float* zbuf   = (const float*)d_in[2];
  const int*   p2f    = (const int*)d_in[3];
  const float* bg     = (const float*)d_in[4];
  float* out = (float*)d_out;
  dim3 grid(NPIX / 256), block(256);
  hipLaunchKernelGGL(RandomPhongShader_kernel, grid, block, 0, stream,
                     colors, dists, zbuf, p2f, bg, out);
}